// Round 10
// baseline (315.465 us; speedup 1.0000x reference)
//
#include <hip/hip_runtime.h>
#include <hip/hip_fp16.h>

#define N_USERS 30000
#define N_ITEMS 60000
#define N_NODES 90000
#define NNZ     2000000
#define D       64
#define N_LAYERS 3
#define OUT_STRIDE ((N_LAYERS + 1) * D)   // 256
#define ROW_CAP 64                        // padded CSR row capacity

#define N_CHUNKS (N_NODES / 16)           // 5625 16-row chunks

typedef __attribute__((ext_vector_type(8))) short bf16x8;   // 8 bf16 = 4 VGPR
typedef __attribute__((ext_vector_type(4))) float f32x4;

// truncating f32 -> bf16 (keeps residual exactly representable)
__device__ __forceinline__ short bf16hi(float x) {
    return (short)(__float_as_uint(x) >> 16);
}
__device__ __forceinline__ float bf16hif(float x) {
    return __uint_as_float(__float_as_uint(x) & 0xffff0000u);
}

// ---------------------------------------------------------------------------
// init: ego = concat(user_emb, item_emb); egoh = f16 copy; out slot 0 = ego
// ---------------------------------------------------------------------------
__global__ void init_ego_kernel(const float* __restrict__ user_emb,
                                const float* __restrict__ item_emb,
                                float* __restrict__ ego,
                                __half* __restrict__ egoh,
                                float* __restrict__ out) {
    int idx = blockIdx.x * blockDim.x + threadIdx.x;   // over N_NODES*D/4 float4s
    const int total = N_NODES * (D / 4);
    if (idx >= total) return;
    int n  = idx / (D / 4);
    int c4 = idx % (D / 4);
    float4 v;
    if (n < N_USERS)
        v = ((const float4*)user_emb)[n * (D / 4) + c4];
    else
        v = ((const float4*)item_emb)[(n - N_USERS) * (D / 4) + c4];
    ((float4*)ego)[idx] = v;
    ((float4*)out)[n * (OUT_STRIDE / 4) + c4] = v;     // slot 0, raw ego
    __half2* hp = (__half2*)egoh;
    hp[idx * 2 + 0] = __floats2half2_rn(v.x, v.y);
    hp[idx * 2 + 1] = __floats2half2_rn(v.z, v.w);
}

// ---------------------------------------------------------------------------
// padded-CSR build, split passes (R5/R8 lesson: the atomic pass and the
// scatter pass MUST be separate kernels -- a scatter that waits on an atomic
// return value serializes ~400cy round trips):
//   seed:  fillpos[r] = r*64
//   hist:  pos[i] = atomicAdd(&fillpos[r], 1)   (coalesced pos store)
//   fill:  pedge[pos[i]] = (col, val)           (no atomics, pipelined)
// hist sits at the device RMW ceiling (~23 G atomics/s, measured R7/R9).
// ---------------------------------------------------------------------------
__global__ void seed_kernel(int* __restrict__ fillpos) {
    int i = blockIdx.x * blockDim.x + threadIdx.x;
    if (i < N_NODES) fillpos[i] = i << 6;
}

__global__ void hist_kernel(const int4* __restrict__ adj_row4,
                            int* __restrict__ fillpos,
                            int4* __restrict__ pos4) {
    int i = blockIdx.x * blockDim.x + threadIdx.x;
    if (i >= NNZ / 4) return;
    int4 r = adj_row4[i];
    int4 p;
    p.x = atomicAdd(&fillpos[r.x], 1);
    p.y = atomicAdd(&fillpos[r.y], 1);
    p.z = atomicAdd(&fillpos[r.z], 1);
    p.w = atomicAdd(&fillpos[r.w], 1);
    pos4[i] = p;
}

__global__ void fill_kernel(const int4* __restrict__ adj_row4,
                            const int4* __restrict__ adj_col4,
                            const float4* __restrict__ adj_val4,
                            const int4* __restrict__ pos4,
                            int2* __restrict__ pedge) {
    int i = blockIdx.x * blockDim.x + threadIdx.x;
    if (i >= NNZ / 4) return;
    int4   r = adj_row4[i];
    int4   c = adj_col4[i];
    float4 v = adj_val4[i];
    int4   p = pos4[i];
    if (p.x < ((r.x + 1) << 6)) pedge[p.x] = make_int2(c.x, __float_as_int(v.x));
    if (p.y < ((r.y + 1) << 6)) pedge[p.y] = make_int2(c.y, __float_as_int(v.y));
    if (p.z < ((r.z + 1) << 6)) pedge[p.z] = make_int2(c.z, __float_as_int(v.z));
    if (p.w < ((r.w + 1) << 6)) pedge[p.w] = make_int2(c.w, __float_as_int(v.w));
}

// ---------------------------------------------------------------------------
// SpMM: side[r][d] = sum over edges of row r: egoh[col][d] * val (f16 gather)
// One wave per row. f16 row = 128B -> 16 lanes x 8B per edge: each gather
// instruction fetches FOUR edges (h = lane>>4 picks the edge, li = lane&15
// covers features 4li..4li+3). 8 quad-gathers = 32 edges in flight per
// iteration; 98% of rows (Poisson lambda~22) finish in ONE iteration.
// Pad lanes have col=0,val=0 (gather row 0, contribute 0 -- L1-hot, free).
// h-group reduce via shfl_xor(16,32); lanes h==0 store float4.
// ---------------------------------------------------------------------------
__global__ __launch_bounds__(256) void spmm_kernel(const int* __restrict__ fillpos,
                                                   const int2* __restrict__ pedge,
                                                   const __half* __restrict__ egoh,
                                                   float* __restrict__ side) {
    int wave = (blockIdx.x * blockDim.x + threadIdx.x) >> 6;
    int lane = threadIdx.x & 63;
    if (wave >= N_NODES) return;
    int beg = wave << 6;
    int cnt = min(fillpos[wave] - beg, ROW_CAP);       // 0..64

    int2 e = make_int2(0, 0);
    if (lane < cnt) e = pedge[beg + lane];
    int cl = e.x;
    int vl = e.y;
    int h  = lane >> 4;          // which edge of the quad this lane serves
    int li = lane & 15;          // feature quad: features 4li..4li+3

    float a0 = 0.f, a1 = 0.f, a2 = 0.f, a3 = 0.f;

    for (int j = 0; j < cnt; j += 32) {                // 8 quads = 32 edges
        // all 8 column broadcasts + 8 gathers issue before any FMA
        int c0 = __shfl(cl, j +  0 + h);
        int c1 = __shfl(cl, j +  4 + h);
        int c2 = __shfl(cl, j +  8 + h);
        int c3 = __shfl(cl, j + 12 + h);
        int c4 = __shfl(cl, j + 16 + h);
        int c5 = __shfl(cl, j + 20 + h);
        int c6 = __shfl(cl, j + 24 + h);
        int c7 = __shfl(cl, j + 28 + h);
        uint2 u0 = *(const uint2*)(egoh + ((size_t)c0 << 6) + (li << 2));
        uint2 u1 = *(const uint2*)(egoh + ((size_t)c1 << 6) + (li << 2));
        uint2 u2 = *(const uint2*)(egoh + ((size_t)c2 << 6) + (li << 2));
        uint2 u3 = *(const uint2*)(egoh + ((size_t)c3 << 6) + (li << 2));
        uint2 u4 = *(const uint2*)(egoh + ((size_t)c4 << 6) + (li << 2));
        uint2 u5 = *(const uint2*)(egoh + ((size_t)c5 << 6) + (li << 2));
        uint2 u6 = *(const uint2*)(egoh + ((size_t)c6 << 6) + (li << 2));
        uint2 u7 = *(const uint2*)(egoh + ((size_t)c7 << 6) + (li << 2));
        float v0 = __int_as_float(__shfl(vl, j +  0 + h));
        float v1 = __int_as_float(__shfl(vl, j +  4 + h));
        float v2 = __int_as_float(__shfl(vl, j +  8 + h));
        float v3 = __int_as_float(__shfl(vl, j + 12 + h));
        float v4 = __int_as_float(__shfl(vl, j + 16 + h));
        float v5 = __int_as_float(__shfl(vl, j + 20 + h));
        float v6 = __int_as_float(__shfl(vl, j + 24 + h));
        float v7 = __int_as_float(__shfl(vl, j + 28 + h));
#define QUAD_FMA(U, V)                                                        \
        {                                                                     \
            float2 fa = __half22float2(*reinterpret_cast<__half2*>(&U.x));    \
            float2 fb = __half22float2(*reinterpret_cast<__half2*>(&U.y));    \
            a0 = fmaf(fa.x, V, a0);                                           \
            a1 = fmaf(fa.y, V, a1);                                           \
            a2 = fmaf(fb.x, V, a2);                                           \
            a3 = fmaf(fb.y, V, a3);                                           \
        }
        QUAD_FMA(u0, v0) QUAD_FMA(u1, v1) QUAD_FMA(u2, v2) QUAD_FMA(u3, v3)
        QUAD_FMA(u4, v4) QUAD_FMA(u5, v5) QUAD_FMA(u6, v6) QUAD_FMA(u7, v7)
#undef QUAD_FMA
    }

    // combine the 4 h-groups (lane = h*16 + li)
    a0 += __shfl_xor(a0, 16); a0 += __shfl_xor(a0, 32);
    a1 += __shfl_xor(a1, 16); a1 += __shfl_xor(a1, 32);
    a2 += __shfl_xor(a2, 16); a2 += __shfl_xor(a2, 32);
    a3 += __shfl_xor(a3, 16); a3 += __shfl_xor(a3, 32);

    if (h == 0) {
        float4 st = {a0, a1, a2, a3};
        *(float4*)(side + ((size_t)wave << 6) + (li << 2)) = st;
    }
}

// ---------------------------------------------------------------------------
// dense via MFMA (hi/lo bf16 split, 3-term). In-place ego update (row-local).
// Also emits f16 ego for next spmm.
// k-map bijective & identical for A/B; C/D layout HW-verified (m89).
// ---------------------------------------------------------------------------
__global__ __launch_bounds__(512) void dense_mfma_kernel(
        const float* __restrict__ side,
        float* __restrict__ ego,          // in/out (row-local update)
        const float* __restrict__ Wgc,
        const float* __restrict__ bgc,
        const float* __restrict__ Wbi,
        const float* __restrict__ bbi,
        __half* __restrict__ egoh,        // out
        float* __restrict__ out,
        int slot) {
    // [mat][hilo][ntile][kstep][lane] : 2*2*4*2*64 frags * 16B = 32 KB
    __shared__ bf16x8 packB[2][2][4][2][64];

    int tid  = threadIdx.x;
    int lane = tid & 63;
    int wib  = tid >> 6;                 // 8 waves/block
    int g    = lane >> 4;                // 0..3
    int li   = lane & 15;                // 0..15

    for (int it = wib; it < 16; it += 8) {
        int mat = it >> 3;               // 0..1
        int t   = (it >> 1) & 3;         // 0..3
        int q   = it & 1;                // 0..1
        const float* W = mat ? Wbi : Wgc;
        bf16x8 fh, fl;
#pragma unroll
        for (int j = 0; j < 8; j++) {
            int k = q * 32 + g * 8 + j;
            float w = W[k * D + t * 16 + li];
            float whf = bf16hif(w);
            fh[j] = bf16hi(w);
            fl[j] = bf16hi(w - whf);
        }
        packB[mat][0][t][q][lane] = fh;
        packB[mat][1][t][q][lane] = fl;
    }
    __syncthreads();

    float biasgc[4], biasbi[4];
#pragma unroll
    for (int t = 0; t < 4; t++) {
        biasgc[t] = bgc[t * 16 + li];
        biasbi[t] = bbi[t * 16 + li];
    }

    int wid = blockIdx.x * 8 + wib;
    int nw  = gridDim.x * 8;

    for (int c = wid; c < N_CHUNKS; c += nw) {
        int rbase = c * 16;
        const float* srow = side + (size_t)(rbase + li) * D;
        const float* erow = ego  + (size_t)(rbase + li) * D;

        f32x4 s0 = *(const f32x4*)(srow + g * 8);
        f32x4 s1 = *(const f32x4*)(srow + g * 8 + 4);
        f32x4 s2 = *(const f32x4*)(srow + 32 + g * 8);
        f32x4 s3 = *(const f32x4*)(srow + 32 + g * 8 + 4);
        f32x4 e0 = *(const f32x4*)(erow + g * 8);
        f32x4 e1 = *(const f32x4*)(erow + g * 8 + 4);
        f32x4 e2 = *(const f32x4*)(erow + 32 + g * 8);
        f32x4 e3 = *(const f32x4*)(erow + 32 + g * 8 + 4);

        bf16x8 sh[2], sl[2], ph[2], pl[2];
#pragma unroll
        for (int j = 0; j < 4; j++) {
            float sa = s0[j], sb = s1[j], sc = s2[j], sd = s3[j];
            float pa = e0[j] * sa, pb = e1[j] * sb, pc = e2[j] * sc, pd = e3[j] * sd;
            sh[0][j]     = bf16hi(sa); sl[0][j]     = bf16hi(sa - bf16hif(sa));
            sh[0][4 + j] = bf16hi(sb); sl[0][4 + j] = bf16hi(sb - bf16hif(sb));
            sh[1][j]     = bf16hi(sc); sl[1][j]     = bf16hi(sc - bf16hif(sc));
            sh[1][4 + j] = bf16hi(sd); sl[1][4 + j] = bf16hi(sd - bf16hif(sd));
            ph[0][j]     = bf16hi(pa); pl[0][j]     = bf16hi(pa - bf16hif(pa));
            ph[0][4 + j] = bf16hi(pb); pl[0][4 + j] = bf16hi(pb - bf16hif(pb));
            ph[1][j]     = bf16hi(pc); pl[1][j]     = bf16hi(pc - bf16hif(pc));
            ph[1][4 + j] = bf16hi(pd); pl[1][4 + j] = bf16hi(pd - bf16hif(pd));
        }

        f32x4 accgc[4], accbi[4];
#pragma unroll
        for (int t = 0; t < 4; t++) {
            accgc[t] = (f32x4){biasgc[t], biasgc[t], biasgc[t], biasgc[t]};
            accbi[t] = (f32x4){biasbi[t], biasbi[t], biasbi[t], biasbi[t]};
        }

#pragma unroll
        for (int t = 0; t < 4; t++) {
#pragma unroll
            for (int q = 0; q < 2; q++) {
                bf16x8 bh = packB[0][0][t][q][lane];
                bf16x8 bl = packB[0][1][t][q][lane];
                accgc[t] = __builtin_amdgcn_mfma_f32_16x16x32_bf16(sh[q], bh, accgc[t], 0, 0, 0);
                accgc[t] = __builtin_amdgcn_mfma_f32_16x16x32_bf16(sl[q], bh, accgc[t], 0, 0, 0);
                accgc[t] = __builtin_amdgcn_mfma_f32_16x16x32_bf16(sh[q], bl, accgc[t], 0, 0, 0);
                bf16x8 ch = packB[1][0][t][q][lane];
                bf16x8 cl2 = packB[1][1][t][q][lane];
                accbi[t] = __builtin_amdgcn_mfma_f32_16x16x32_bf16(ph[q], ch, accbi[t], 0, 0, 0);
                accbi[t] = __builtin_amdgcn_mfma_f32_16x16x32_bf16(pl[q], ch, accbi[t], 0, 0, 0);
                accbi[t] = __builtin_amdgcn_mfma_f32_16x16x32_bf16(ph[q], cl2, accbi[t], 0, 0, 0);
            }
        }

        float en[4][4];
        float ss[4] = {0.f, 0.f, 0.f, 0.f};
#pragma unroll
        for (int t = 0; t < 4; t++) {
#pragma unroll
            for (int r = 0; r < 4; r++) {
                float a1 = accgc[t][r]; a1 = a1 > 0.f ? a1 : 0.2f * a1;
                float a2 = accbi[t][r]; a2 = a2 > 0.f ? a2 : 0.2f * a2;
                float e = a1 + a2;
                en[t][r] = e;
                ss[r] += e * e;
            }
        }
#pragma unroll
        for (int r = 0; r < 4; r++) {
            float s = ss[r];
            s += __shfl_xor(s, 8);
            s += __shfl_xor(s, 4);
            s += __shfl_xor(s, 2);
            s += __shfl_xor(s, 1);
            float inv = 1.0f / fmaxf(sqrtf(s), 1e-12f);
            int row = rbase + g * 4 + r;
#pragma unroll
            for (int t = 0; t < 4; t++) {
                ego [(size_t)row * D + t * 16 + li] = en[t][r];
                egoh[(size_t)row * D + t * 16 + li] = __float2half(en[t][r]);
                out[(size_t)row * OUT_STRIDE + slot * D + t * 16 + li] = en[t][r] * inv;
            }
        }
    }
}

// ---------------------------------------------------------------------------
extern "C" void kernel_launch(void* const* d_in, const int* in_sizes, int n_in,
                              void* d_out, int out_size, void* d_ws, size_t ws_size,
                              hipStream_t stream) {
    const float* user_emb = (const float*)d_in[0];
    const float* item_emb = (const float*)d_in[1];
    const int*   adj_row  = (const int*)d_in[2];
    const int*   adj_col  = (const int*)d_in[3];
    const float* adj_val  = (const float*)d_in[4];
    const float* W_gc     = (const float*)d_in[5];
    const float* b_gc     = (const float*)d_in[6];
    const float* W_bi     = (const float*)d_in[7];
    const float* b_bi     = (const float*)d_in[8];
    float* out = (float*)d_out;

    char* ws = (char*)d_ws;
    size_t off = 0;
    auto alloc = [&](size_t bytes) -> void* {
        void* p = ws + off;
        off += (bytes + 255) / 256 * 256;
        return p;
    };
    float*  ego     = (float*)alloc((size_t)N_NODES * D * 4);
    __half* egoh    = (__half*)alloc((size_t)N_NODES * D * 2);
    float*  side    = (float*)alloc((size_t)N_NODES * D * 4);
    int*    fillpos = (int*)alloc((size_t)N_NODES * 4);
    int*    pos     = (int*)alloc((size_t)NNZ * 4);
    int2*   pedge   = (int2*)alloc((size_t)N_NODES * ROW_CAP * 8);  // 46 MB

    seed_kernel<<<(N_NODES + 255) / 256, 256, 0, stream>>>(fillpos);
    hist_kernel<<<(NNZ / 4 + 255) / 256, 256, 0, stream>>>(
        (const int4*)adj_row, fillpos, (int4*)pos);
    fill_kernel<<<(NNZ / 4 + 255) / 256, 256, 0, stream>>>(
        (const int4*)adj_row, (const int4*)adj_col, (const float4*)adj_val,
        (const int4*)pos, pedge);

    init_ego_kernel<<<(N_NODES * (D / 4) + 255) / 256, 256, 0, stream>>>(
        user_emb, item_emb, ego, egoh, out);

    for (int k = 0; k < N_LAYERS; k++) {
        spmm_kernel<<<(N_NODES + 3) / 4, 256, 0, stream>>>(
            fillpos, pedge, egoh, side);
        dense_mfma_kernel<<<352, 512, 0, stream>>>(
            side, ego,
            W_gc + (size_t)k * D * D, b_gc + (size_t)k * D,
            W_bi + (size_t)k * D * D, b_bi + (size_t)k * D,
            egoh, out, k + 1);
    }
}

// Round 11
// 284.203 us; speedup vs baseline: 1.1100x; 1.1100x over previous
//
#include <hip/hip_runtime.h>
#include <hip/hip_fp16.h>

#define N_USERS 30000
#define N_ITEMS 60000
#define N_NODES 90000
#define NNZ     2000000
#define D       64
#define N_LAYERS 3
#define OUT_STRIDE ((N_LAYERS + 1) * D)   // 256
#define ROW_CAP 64                        // padded CSR row capacity

#define N_CHUNKS (N_NODES / 16)           // 5625 16-row chunks

typedef __attribute__((ext_vector_type(8))) _Float16 f16x8;  // 8 f16 = 4 VGPR
typedef __attribute__((ext_vector_type(4))) float f32x4;

// ---------------------------------------------------------------------------
// init: egoh = f16 concat(user_emb, item_emb); out slot 0 = raw f32 ego
// ---------------------------------------------------------------------------
__global__ void init_ego_kernel(const float* __restrict__ user_emb,
                                const float* __restrict__ item_emb,
                                __half* __restrict__ egoh,
                                float* __restrict__ out) {
    int idx = blockIdx.x * blockDim.x + threadIdx.x;   // over N_NODES*D/4 float4s
    const int total = N_NODES * (D / 4);
    if (idx >= total) return;
    int n  = idx / (D / 4);
    int c4 = idx % (D / 4);
    float4 v;
    if (n < N_USERS)
        v = ((const float4*)user_emb)[n * (D / 4) + c4];
    else
        v = ((const float4*)item_emb)[(n - N_USERS) * (D / 4) + c4];
    ((float4*)out)[n * (OUT_STRIDE / 4) + c4] = v;     // slot 0, raw ego
    __half2 lo = __floats2half2_rn(v.x, v.y);
    __half2 hi = __floats2half2_rn(v.z, v.w);
    uint2 st = {*(unsigned*)&lo, *(unsigned*)&hi};
    *(uint2*)(egoh + (size_t)n * D + c4 * 4) = st;
}

// ---------------------------------------------------------------------------
// padded-CSR build, split passes (R5/R8 lesson: the atomic pass and the
// scatter pass MUST be separate kernels -- a scatter that waits on an atomic
// return value serializes ~400cy round trips):
//   seed:  fillpos[r] = r*64
//   hist:  pos[i] = atomicAdd(&fillpos[r], 1)   (coalesced pos store)
//   fill:  pedge[pos[i]] = (col, val)           (no atomics, pipelined)
// hist sits at the device RMW ceiling (~23 G returning atomics/s, measured
// R7/R9/R10 -- ILP and pass structure do not move it).
// ---------------------------------------------------------------------------
__global__ void seed_kernel(int* __restrict__ fillpos) {
    int i = blockIdx.x * blockDim.x + threadIdx.x;
    if (i < N_NODES) fillpos[i] = i << 6;
}

__global__ void hist_kernel(const int4* __restrict__ adj_row4,
                            int* __restrict__ fillpos,
                            int4* __restrict__ pos4) {
    int i = blockIdx.x * blockDim.x + threadIdx.x;
    if (i >= NNZ / 4) return;
    int4 r = adj_row4[i];
    int4 p;
    p.x = atomicAdd(&fillpos[r.x], 1);
    p.y = atomicAdd(&fillpos[r.y], 1);
    p.z = atomicAdd(&fillpos[r.z], 1);
    p.w = atomicAdd(&fillpos[r.w], 1);
    pos4[i] = p;
}

__global__ void fill_kernel(const int4* __restrict__ adj_row4,
                            const int4* __restrict__ adj_col4,
                            const float4* __restrict__ adj_val4,
                            const int4* __restrict__ pos4,
                            int2* __restrict__ pedge) {
    int i = blockIdx.x * blockDim.x + threadIdx.x;
    if (i >= NNZ / 4) return;
    int4   r = adj_row4[i];
    int4   c = adj_col4[i];
    float4 v = adj_val4[i];
    int4   p = pos4[i];
    if (p.x < ((r.x + 1) << 6)) pedge[p.x] = make_int2(c.x, __float_as_int(v.x));
    if (p.y < ((r.y + 1) << 6)) pedge[p.y] = make_int2(c.y, __float_as_int(v.y));
    if (p.z < ((r.z + 1) << 6)) pedge[p.z] = make_int2(c.z, __float_as_int(v.z));
    if (p.w < ((r.w + 1) << 6)) pedge[p.w] = make_int2(c.w, __float_as_int(v.w));
}

// ---------------------------------------------------------------------------
// SpMM: side[r][d] = sum over edges of row r: egoh[col][d] * val (f16 gather)
// One wave per row; 16 lanes x 8B per edge; 8 quad-gathers (32 edges) in
// flight. Gather-BW bound (R10 diagnostic: unroll depth does not move it;
// ~6 TB/s effective on 2M x 128B random gathers). side stored as f16.
// ---------------------------------------------------------------------------
__global__ __launch_bounds__(256) void spmm_kernel(const int* __restrict__ fillpos,
                                                   const int2* __restrict__ pedge,
                                                   const __half* __restrict__ egoh,
                                                   __half* __restrict__ side) {
    int wave = (blockIdx.x * blockDim.x + threadIdx.x) >> 6;
    int lane = threadIdx.x & 63;
    if (wave >= N_NODES) return;
    int beg = wave << 6;
    int cnt = min(fillpos[wave] - beg, ROW_CAP);       // 0..64

    int2 e = make_int2(0, 0);
    if (lane < cnt) e = pedge[beg + lane];
    int cl = e.x;
    int vl = e.y;
    int h  = lane >> 4;          // which edge of the quad this lane serves
    int li = lane & 15;          // feature quad: features 4li..4li+3

    float a0 = 0.f, a1 = 0.f, a2 = 0.f, a3 = 0.f;

    for (int j = 0; j < cnt; j += 32) {                // 8 quads = 32 edges
        int c0 = __shfl(cl, j +  0 + h);
        int c1 = __shfl(cl, j +  4 + h);
        int c2 = __shfl(cl, j +  8 + h);
        int c3 = __shfl(cl, j + 12 + h);
        int c4 = __shfl(cl, j + 16 + h);
        int c5 = __shfl(cl, j + 20 + h);
        int c6 = __shfl(cl, j + 24 + h);
        int c7 = __shfl(cl, j + 28 + h);
        uint2 u0 = *(const uint2*)(egoh + ((size_t)c0 << 6) + (li << 2));
        uint2 u1 = *(const uint2*)(egoh + ((size_t)c1 << 6) + (li << 2));
        uint2 u2 = *(const uint2*)(egoh + ((size_t)c2 << 6) + (li << 2));
        uint2 u3 = *(const uint2*)(egoh + ((size_t)c3 << 6) + (li << 2));
        uint2 u4 = *(const uint2*)(egoh + ((size_t)c4 << 6) + (li << 2));
        uint2 u5 = *(const uint2*)(egoh + ((size_t)c5 << 6) + (li << 2));
        uint2 u6 = *(const uint2*)(egoh + ((size_t)c6 << 6) + (li << 2));
        uint2 u7 = *(const uint2*)(egoh + ((size_t)c7 << 6) + (li << 2));
        float v0 = __int_as_float(__shfl(vl, j +  0 + h));
        float v1 = __int_as_float(__shfl(vl, j +  4 + h));
        float v2 = __int_as_float(__shfl(vl, j +  8 + h));
        float v3 = __int_as_float(__shfl(vl, j + 12 + h));
        float v4 = __int_as_float(__shfl(vl, j + 16 + h));
        float v5 = __int_as_float(__shfl(vl, j + 20 + h));
        float v6 = __int_as_float(__shfl(vl, j + 24 + h));
        float v7 = __int_as_float(__shfl(vl, j + 28 + h));
#define QUAD_FMA(U, V)                                                        \
        {                                                                     \
            float2 fa = __half22float2(*reinterpret_cast<__half2*>(&U.x));    \
            float2 fb = __half22float2(*reinterpret_cast<__half2*>(&U.y));    \
            a0 = fmaf(fa.x, V, a0);                                           \
            a1 = fmaf(fa.y, V, a1);                                           \
            a2 = fmaf(fb.x, V, a2);                                           \
            a3 = fmaf(fb.y, V, a3);                                           \
        }
        QUAD_FMA(u0, v0) QUAD_FMA(u1, v1) QUAD_FMA(u2, v2) QUAD_FMA(u3, v3)
        QUAD_FMA(u4, v4) QUAD_FMA(u5, v5) QUAD_FMA(u6, v6) QUAD_FMA(u7, v7)
#undef QUAD_FMA
    }

    a0 += __shfl_xor(a0, 16); a0 += __shfl_xor(a0, 32);
    a1 += __shfl_xor(a1, 16); a1 += __shfl_xor(a1, 32);
    a2 += __shfl_xor(a2, 16); a2 += __shfl_xor(a2, 32);
    a3 += __shfl_xor(a3, 16); a3 += __shfl_xor(a3, 32);

    if (h == 0) {
        __half2 lo = __floats2half2_rn(a0, a1);
        __half2 hi = __floats2half2_rn(a2, a3);
        uint2 st = {*(unsigned*)&lo, *(unsigned*)&hi};
        *(uint2*)(side + ((size_t)wave << 6) + (li << 2)) = st;
    }
}

// ---------------------------------------------------------------------------
// dense via single-pass f16 MFMA (inputs already f16 -> no hi/lo split):
//   sum_e = lrelu(side@Wgc+bgc); bi_e = lrelu((ego*side)@Wbi+bbi)
//   ego_out = sum_e + bi_e ; out slot = l2norm(ego_out)
// In-place egoh update (row-local). W as f16 (err ~1e-4, invisible vs 1e-2).
// k-map bijective & identical for A/B; C/D layout dtype-independent (m89+).
// ---------------------------------------------------------------------------
__global__ __launch_bounds__(512) void dense_mfma_kernel(
        const __half* __restrict__ side,
        __half* __restrict__ egoh,        // in/out (row-local update)
        const float* __restrict__ Wgc,
        const float* __restrict__ bgc,
        const float* __restrict__ Wbi,
        const float* __restrict__ bbi,
        float* __restrict__ out,
        int slot) {
    // [mat][ntile][kstep][lane] : 2*4*2*64 frags * 16B = 16 KB
    __shared__ f16x8 packW[2][4][2][64];

    int tid  = threadIdx.x;
    int lane = tid & 63;
    int wib  = tid >> 6;                 // 8 waves/block
    int g    = lane >> 4;                // 0..3
    int li   = lane & 15;                // 0..15

    for (int it = wib; it < 16; it += 8) {
        int mat = it >> 3;               // 0..1
        int t   = (it >> 1) & 3;         // 0..3
        int q   = it & 1;                // 0..1
        const float* W = mat ? Wbi : Wgc;
        f16x8 f;
#pragma unroll
        for (int j = 0; j < 8; j++) {
            int k = q * 32 + g * 8 + j;
            f[j] = (_Float16)W[k * D + t * 16 + li];
        }
        packW[mat][t][q][lane] = f;
    }
    __syncthreads();

    float biasgc[4], biasbi[4];
#pragma unroll
    for (int t = 0; t < 4; t++) {
        biasgc[t] = bgc[t * 16 + li];
        biasbi[t] = bbi[t * 16 + li];
    }

    int wid = blockIdx.x * 8 + wib;
    int nw  = gridDim.x * 8;

    for (int c = wid; c < N_CHUNKS; c += nw) {
        int rbase = c * 16;
        const __half* srow = side + (size_t)(rbase + li) * D;
        const __half* erow = egoh + (size_t)(rbase + li) * D;

        // lane (g,li): A-frag elems k = q*32 + g*8 + j  (two 16B loads each)
        f16x8 sf0 = *(const f16x8*)(srow + g * 8);
        f16x8 sf1 = *(const f16x8*)(srow + 32 + g * 8);
        f16x8 ef0 = *(const f16x8*)(erow + g * 8);
        f16x8 ef1 = *(const f16x8*)(erow + 32 + g * 8);
        f16x8 pf0 = sf0 * ef0;           // elementwise f16 product
        f16x8 pf1 = sf1 * ef1;

        f32x4 accgc[4], accbi[4];
#pragma unroll
        for (int t = 0; t < 4; t++) {
            accgc[t] = (f32x4){biasgc[t], biasgc[t], biasgc[t], biasgc[t]};
            accbi[t] = (f32x4){biasbi[t], biasbi[t], biasbi[t], biasbi[t]};
        }

#pragma unroll
        for (int t = 0; t < 4; t++) {
            accgc[t] = __builtin_amdgcn_mfma_f32_16x16x32_f16(sf0, packW[0][t][0][lane], accgc[t], 0, 0, 0);
            accgc[t] = __builtin_amdgcn_mfma_f32_16x16x32_f16(sf1, packW[0][t][1][lane], accgc[t], 0, 0, 0);
            accbi[t] = __builtin_amdgcn_mfma_f32_16x16x32_f16(pf0, packW[1][t][0][lane], accbi[t], 0, 0, 0);
            accbi[t] = __builtin_amdgcn_mfma_f32_16x16x32_f16(pf1, packW[1][t][1][lane], accbi[t], 0, 0, 0);
        }

        // epilogue: lrelu + sum, l2 norm per row (row = rbase + g*4 + reg)
        float en[4][4];
        float ss[4] = {0.f, 0.f, 0.f, 0.f};
#pragma unroll
        for (int t = 0; t < 4; t++) {
#pragma unroll
            for (int r = 0; r < 4; r++) {
                float a1 = accgc[t][r]; a1 = a1 > 0.f ? a1 : 0.2f * a1;
                float a2 = accbi[t][r]; a2 = a2 > 0.f ? a2 : 0.2f * a2;
                float e = a1 + a2;
                en[t][r] = e;
                ss[r] += e * e;
            }
        }
#pragma unroll
        for (int r = 0; r < 4; r++) {
            float s = ss[r];
            s += __shfl_xor(s, 8);
            s += __shfl_xor(s, 4);
            s += __shfl_xor(s, 2);
            s += __shfl_xor(s, 1);
            float inv = 1.0f / fmaxf(sqrtf(s), 1e-12f);
            int row = rbase + g * 4 + r;
#pragma unroll
            for (int t = 0; t < 4; t++) {
                egoh[(size_t)row * D + t * 16 + li] = __float2half(en[t][r]);
                out[(size_t)row * OUT_STRIDE + slot * D + t * 16 + li] = en[t][r] * inv;
            }
        }
    }
}

// ---------------------------------------------------------------------------
extern "C" void kernel_launch(void* const* d_in, const int* in_sizes, int n_in,
                              void* d_out, int out_size, void* d_ws, size_t ws_size,
                              hipStream_t stream) {
    const float* user_emb = (const float*)d_in[0];
    const float* item_emb = (const float*)d_in[1];
    const int*   adj_row  = (const int*)d_in[2];
    const int*   adj_col  = (const int*)d_in[3];
    const float* adj_val  = (const float*)d_in[4];
    const float* W_gc     = (const float*)d_in[5];
    const float* b_gc     = (const float*)d_in[6];
    const float* W_bi     = (const float*)d_in[7];
    const float* b_bi     = (const float*)d_in[8];
    float* out = (float*)d_out;

    char* ws = (char*)d_ws;
    size_t off = 0;
    auto alloc = [&](size_t bytes) -> void* {
        void* p = ws + off;
        off += (bytes + 255) / 256 * 256;
        return p;
    };
    __half* egoh    = (__half*)alloc((size_t)N_NODES * D * 2);
    __half* side    = (__half*)alloc((size_t)N_NODES * D * 2);
    int*    fillpos = (int*)alloc((size_t)N_NODES * 4);
    int*    pos     = (int*)alloc((size_t)NNZ * 4);
    int2*   pedge   = (int2*)alloc((size_t)N_NODES * ROW_CAP * 8);  // 46 MB

    seed_kernel<<<(N_NODES + 255) / 256, 256, 0, stream>>>(fillpos);
    hist_kernel<<<(NNZ / 4 + 255) / 256, 256, 0, stream>>>(
        (const int4*)adj_row, fillpos, (int4*)pos);
    fill_kernel<<<(NNZ / 4 + 255) / 256, 256, 0, stream>>>(
        (const int4*)adj_row, (const int4*)adj_col, (const float4*)adj_val,
        (const int4*)pos, pedge);

    init_ego_kernel<<<(N_NODES * (D / 4) + 255) / 256, 256, 0, stream>>>(
        user_emb, item_emb, egoh, out);

    for (int k = 0; k < N_LAYERS; k++) {
        spmm_kernel<<<(N_NODES + 3) / 4, 256, 0, stream>>>(
            fillpos, pedge, egoh, side);
        dense_mfma_kernel<<<352, 512, 0, stream>>>(
            side, egoh,
            W_gc + (size_t)k * D * D, b_gc + (size_t)k * D,
            W_bi + (size_t)k * D * D, b_bi + (size_t)k * D,
            out, k + 1);
    }
}